// Round 4
// baseline (171.549 us; speedup 1.0000x reference)
//
#include <hip/hip_runtime.h>

#define EPSILON 0.05f
#define NSLOTS 64

typedef float v4f __attribute__((ext_vector_type(4)));

// One wave per ray. The 8 global_load_dwordx4 (4 KB z + 4 KB w per wave) are
// issued back-to-back in ONE asm volatile block before a single
// s_waitcnt vmcnt(0) -- guaranteeing 8 loads (8 KB/wave) in flight, which the
// compiler's register scheduler refused to do from C++ (R1: VGPR=24, R2:
// VGPR=36 => <=4-5 in flight => 2.3 TB/s latency wall). Base pointers are
// wave-uniform (readfirstlane) -> SGPR base + one VGPR offset (lane*16) +
// 13-bit immediate offsets 0/1024/2048/3072.
__global__ __launch_bounds__(256, 8) void sight_near_loss_1024(
    const float* __restrict__ ray_depth,   // [N]
    const float* __restrict__ z_vals,      // [N, 1024]
    const float* __restrict__ weights,     // [N, 1024]
    const int*   __restrict__ ray_mask,    // [N]
    float* __restrict__ partials,          // [3*NSLOTS]
    int n_rays)
{
    const int lane = threadIdx.x & 63;
    const int r = __builtin_amdgcn_readfirstlane(blockIdx.x * 4 + (threadIdx.x >> 6));
    if (r >= n_rays) return;

    // uniform scalar loads (issued before the data loads; covered by the
    // same waitcnt -- no extra serialized round-trip)
    const float d   = ray_depth[r];
    const int   msk = ray_mask[r];

    const float* zb = z_vals  + (size_t)r * 1024;
    const float* wb = weights + (size_t)r * 1024;
    const int voff = lane * 16;

    v4f z0, z1, z2, z3, w0, w1, w2, w3;
    asm volatile(
        "global_load_dwordx4 %0, %8, %9 offset:0\n\t"
        "global_load_dwordx4 %1, %8, %9 offset:1024\n\t"
        "global_load_dwordx4 %2, %8, %9 offset:2048\n\t"
        "global_load_dwordx4 %3, %8, %9 offset:3072\n\t"
        "global_load_dwordx4 %4, %8, %10 offset:0\n\t"
        "global_load_dwordx4 %5, %8, %10 offset:1024\n\t"
        "global_load_dwordx4 %6, %8, %10 offset:2048\n\t"
        "global_load_dwordx4 %7, %8, %10 offset:3072\n\t"
        "s_waitcnt vmcnt(0)"
        : "=v"(z0), "=v"(z1), "=v"(z2), "=v"(z3),
          "=v"(w0), "=v"(w1), "=v"(w2), "=v"(w3)
        : "v"(voff), "s"(zb), "s"(wb)
        : "memory");

    const float lo = d - EPSILON;
    const float hi = d + EPSILON;

    float empty = 0.0f, wnear = 0.0f;
    {
        v4f zz[4] = {z0, z1, z2, z3};
        v4f ww[4] = {w0, w1, w2, w3};
        #pragma unroll
        for (int k = 0; k < 4; ++k) {
            #pragma unroll
            for (int c = 0; c < 4; ++c) {
                const float z = zz[k][c];
                const float w = ww[k][c];
                empty += (z < lo) ? w * w : 0.0f;
                wnear += (z >= lo && z < hi) ? w : 0.0f;
            }
        }
    }

    #pragma unroll
    for (int off = 32; off > 0; off >>= 1) {
        empty += __shfl_xor(empty, off, 64);
        wnear += __shfl_xor(wnear, off, 64);
    }

    if (lane == 0 && msk != 0) {
        const int slot = r & (NSLOTS - 1);
        const float t = 1.0f - wnear;
        atomicAdd(&partials[slot],              empty);
        atomicAdd(&partials[NSLOTS + slot],     t * t);
        atomicAdd(&partials[2 * NSLOTS + slot], 1.0f);
    }
}

// Generic fallback (runtime S)
__global__ __launch_bounds__(256) void sight_near_loss_generic(
    const float* __restrict__ ray_depth,
    const float* __restrict__ z_vals,
    const float* __restrict__ weights,
    const int*   __restrict__ ray_mask,
    float* __restrict__ partials,
    int n_rays, int S)
{
    const int wave = threadIdx.x >> 6;
    const int lane = threadIdx.x & 63;
    const int r = blockIdx.x * 4 + wave;
    if (r >= n_rays) return;

    const float d  = ray_depth[r];
    const float lo = d - EPSILON;
    const float hi = d + EPSILON;

    float empty = 0.0f, wnear = 0.0f;
    const float* zr = z_vals  + (size_t)r * S;
    const float* wr = weights + (size_t)r * S;
    for (int k = lane; k < S; k += 64) {
        const float z = zr[k];
        const float w = wr[k];
        empty += (z < lo) ? w * w : 0.0f;
        wnear += (z >= lo && z < hi) ? w : 0.0f;
    }
    #pragma unroll
    for (int off = 32; off > 0; off >>= 1) {
        empty += __shfl_xor(empty, off, 64);
        wnear += __shfl_xor(wnear, off, 64);
    }
    if (lane == 0 && ray_mask[r] != 0) {
        const int slot = r & (NSLOTS - 1);
        const float t = 1.0f - wnear;
        atomicAdd(&partials[slot],              empty);
        atomicAdd(&partials[NSLOTS + slot],     t * t);
        atomicAdd(&partials[2 * NSLOTS + slot], 1.0f);
    }
}

__global__ void sight_near_finalize_kernel(
    const float* __restrict__ partials, float* __restrict__ out)
{
    const int lane = threadIdx.x;  // 64 threads
    float e = partials[lane];
    float n = partials[NSLOTS + lane];
    float m = partials[2 * NSLOTS + lane];
    #pragma unroll
    for (int off = 32; off > 0; off >>= 1) {
        e += __shfl_xor(e, off, 64);
        n += __shfl_xor(n, off, 64);
        m += __shfl_xor(m, off, 64);
    }
    if (lane == 0) {
        out[0] = e / m;   // loss_empty
        out[1] = n / m;   // loss_near
    }
}

extern "C" void kernel_launch(void* const* d_in, const int* in_sizes, int n_in,
                              void* d_out, int out_size, void* d_ws, size_t ws_size,
                              hipStream_t stream) {
    const float* ray_depth = (const float*)d_in[0];
    const float* z_vals    = (const float*)d_in[1];
    const float* weights   = (const float*)d_in[2];
    const int*   ray_mask  = (const int*)d_in[3];

    const int n_rays = in_sizes[0];                // ray_depth is [N,1]
    const int S      = in_sizes[1] / n_rays;       // 1024

    float* partials = (float*)d_ws;
    hipMemsetAsync(partials, 0, 3 * NSLOTS * sizeof(float), stream);

    if (S == 1024) {
        const int blocks = (n_rays + 3) / 4;       // 4 waves (rays) per block
        sight_near_loss_1024<<<blocks, 256, 0, stream>>>(
            ray_depth, z_vals, weights, ray_mask, partials, n_rays);
    } else {
        const int blocks = (n_rays + 3) / 4;
        sight_near_loss_generic<<<blocks, 256, 0, stream>>>(
            ray_depth, z_vals, weights, ray_mask, partials, n_rays, S);
    }
    sight_near_finalize_kernel<<<1, 64, 0, stream>>>(partials, (float*)d_out);
}